// Round 5
// baseline (152.028 us; speedup 1.0000x reference)
//
#include <hip/hip_runtime.h>
#include <hip/hip_bf16.h>

// Problem constants
#define BB 128        // batch
#define NN 100000     // memory bank size
#define DD 256        // feature dim (K)
#define CC 2000       // num classes
#define SS 751        // source classes
#define INVTEMP 20.0f // 1/0.05
#define EPSV 1e-6f

#define HIST_BLOCKS 391   // ceil(100000/256)
#define PREP_BLOCKS 32    // 8192/256
#define GPERS 512         // persistent grid for class_mfma (2 blocks/CU)

typedef __attribute__((ext_vector_type(8))) short bf16x8;   // 8 bf16 in 4 VGPRs
typedef __attribute__((ext_vector_type(8))) unsigned short u16x8;
typedef __attribute__((ext_vector_type(4))) float f32x4;

__device__ __forceinline__ unsigned short f2bf(float x) {
    unsigned int u = __float_as_uint(x);
    u += 0x7fffu + ((u >> 16) & 1u);   // round-to-nearest-even
    return (unsigned short)(u >> 16);
}

// ---------------- fused: histogram + input-fragment prep ----------------
// inb layout: 16B chunk ch = (nr*8 + kc)*64 + l holds
//   row = nr*16 + (l&15)  (rows 0..127 inputs, 128..255 inputs2)
//   k   = kc*32 + (l>>4)*8 + j, j=0..7
__global__ __launch_bounds__(256) void hist_prep_kernel(
    const int* __restrict__ labels, int* __restrict__ counts,
    const float* __restrict__ in1, const float* __restrict__ in2,
    unsigned short* __restrict__ inb)
{
    int bid = blockIdx.x;
    if (bid < HIST_BLOCKS) {
        int n = bid * 256 + threadIdx.x;
        if (n < NN) atomicAdd(&counts[labels[n]], 1);
    } else {
        int ch = (bid - HIST_BLOCKS) * 256 + threadIdx.x;
        if (ch >= 8192) return;
        int l  = ch & 63;
        int kc = (ch >> 6) & 7;
        int nr = ch >> 9;
        int row = nr * 16 + (l & 15);
        const float* src = (row < BB) ? (in1 + (size_t)row * DD)
                                      : (in2 + (size_t)(row - BB) * DD);
        int k0 = kc * 32 + ((l >> 4) << 3);
        u16x8 o;
        #pragma unroll
        for (int j = 0; j < 8; ++j) o[j] = f2bf(src[k0 + j]);
        *(u16x8*)(inb + (size_t)ch * 8) = o;
    }
}

// one block, 256 threads, exclusive scan over 2048 (padded) counts; also zeroes out
__global__ __launch_bounds__(256) void scan_kernel(const int* __restrict__ counts,
                                                   int* __restrict__ offsets,
                                                   int* __restrict__ cursor,
                                                   float* __restrict__ out) {
    const int PT = 8; // 256*8 = 2048 >= CC
    int tid = threadIdx.x;
    if (tid == 0) { out[0] = 0.f; out[1] = 0.f; }
    int vals[PT];
    int tot = 0;
    #pragma unroll
    for (int i = 0; i < PT; ++i) {
        int c = tid * PT + i;
        vals[i] = (c < CC) ? counts[c] : 0;
        tot += vals[i];
    }
    __shared__ int sh[256];
    sh[tid] = tot;
    __syncthreads();
    for (int ofs = 1; ofs < 256; ofs <<= 1) {
        int v = (tid >= ofs) ? sh[tid - ofs] : 0;
        __syncthreads();
        sh[tid] += v;
        __syncthreads();
    }
    int run = sh[tid] - tot;
    #pragma unroll
    for (int i = 0; i < PT; ++i) {
        int c = tid * PT + i;
        if (c < CC) { offsets[c] = run; cursor[c] = run; }
        run += vals[i];
    }
}

__global__ void scatter_kernel(const int* __restrict__ labels, int* __restrict__ cursor,
                               int* __restrict__ sorted_idx) {
    int n = blockIdx.x * 256 + threadIdx.x;
    if (n < NN) {
        int c = labels[n];
        int p = atomicAdd(&cursor[c], 1);
        sorted_idx[p] = n;
    }
}

// ---------------- heavy kernel: persistent, software-pipelined, 2 blocks/CU ----------------
// Grid = GPERS blocks x 512 threads (8 waves). Block walks classes c = bid, bid+GPERS, ...
// LDS A-tile in FRAGMENT ORDER: fragment (ma,kc) = contiguous 1KB; lane l's 16B at
// chunk l^kc. Write side (thread = row m0, k-col s8): chunk (hi*16+(m0&15))^s8 of
// fragment (m0>>4, s8) -> bank-quad (m0^s8)&7, uniform -> conflict-free both sides.
// Pipeline depth 2: gather t+1 into regs while MFMAing t; write LDS after fold;
// one barrier/tile. Wave w: batch cols [32w,+32) (w<4 inputs: sum+max+min; w>=4
// inputs2: sum). Stats transposed [col][CC] for coalesced finalize.
__global__ __launch_bounds__(512, 4) void class_mfma(
    const float* __restrict__ features, const unsigned short* __restrict__ inb,
    const int* __restrict__ offsets, const int* __restrict__ counts,
    const int* __restrict__ sorted_idx,
    float* __restrict__ gsumA, float* __restrict__ gsumB,
    float* __restrict__ gmax, float* __restrict__ gmin)
{
    const int tid = threadIdx.x;
    const int w   = tid >> 6;
    const int l   = tid & 63;
    const int m0  = tid >> 3;  // staging: member row 0..63
    const int s8  = tid & 7;   // staging: 128B f32 segment (= fragment k-column)

    __shared__ __align__(16) char lds[2][32768]; // double-buffered A tile (bf16, fragment order)

    // hoist B (input) fragments: kc 0..7, nb 0..1 -> 16 x bf16x8 (64 VGPR)
    bf16x8 bfr[16];
    #pragma unroll
    for (int kc = 0; kc < 8; ++kc)
        #pragma unroll
        for (int nb = 0; nb < 2; ++nb) {
            int nr = 2 * w + nb;
            bfr[kc * 2 + nb] = *(const bf16x8*)(inb + (((size_t)(nr * 8 + kc) * 64 + l) << 3));
        }

    // staging address constants
    const int frag_base = (((m0 >> 4) * 8 + s8) << 10);   // fragment (m0>>4, s8)
    const int chunk_lo  = (m0 & 15) ^ s8;                  // low 4 bits of chunk

    // ---- tile iterator state (all wave-uniform) ----
    int cc = blockIdx.x;               // current class
    int ccnt = counts[cc], coff = offsets[cc];
    int cbase = 0;

    int nc = cc, ncnt = ccnt, noff = coff, nbase = 64; // next tile
    if (nbase >= ncnt) {
        nc = cc + GPERS; nbase = 0;
        if (nc < CC) { ncnt = counts[nc]; noff = offsets[nc]; }
    }

    // ---- prologue: stage tile 0 into lds[0] ----
    {
        int idx = coff + min(cbase + m0, ccnt - 1);
        int n0  = sorted_idx[idx];
        bool v0 = (cbase + m0) < ccnt;
        const float4* src = (const float4*)(features + (size_t)n0 * DD) + s8 * 8;
        float4 S[8];
        #pragma unroll
        for (int j = 0; j < 8; ++j) S[j] = src[j];
        #pragma unroll
        for (int hi = 0; hi < 4; ++hi) {
            u16x8 o = (u16x8)0;
            if (v0) {
                float4 a = S[2 * hi], b = S[2 * hi + 1];
                o[0] = f2bf(a.x); o[1] = f2bf(a.y); o[2] = f2bf(a.z); o[3] = f2bf(a.w);
                o[4] = f2bf(b.x); o[5] = f2bf(b.y); o[6] = f2bf(b.z); o[7] = f2bf(b.w);
            }
            int byte = frag_base + ((((hi << 4) + chunk_lo)) << 4);
            *(u16x8*)(&lds[0][0] + byte) = o;
        }
    }
    // prefetch midx for next tile
    int midx_n = 0;
    if (nc < CC) midx_n = sorted_idx[noff + min(nbase + m0, ncnt - 1)];
    __syncthreads();

    float s_sum[2] = {0.f, 0.f};
    float s_max[2] = {-3.4e38f, -3.4e38f};
    float s_min[2] = { 3.4e38f,  3.4e38f};

    int buf = 0;

    while (cc < CC) {
        const bool have_n = (nc < CC);

        // (1) issue gather for next tile (midx_n already resident)
        float4 S[8];
        if (have_n) {
            const float4* src = (const float4*)(features + (size_t)midx_n * DD) + s8 * 8;
            #pragma unroll
            for (int j = 0; j < 8; ++j) S[j] = src[j];
        }
        const bool nrow_valid = have_n && (nbase + m0 < ncnt);

        // (2) advance to after-next tile; prefetch its midx
        int ac = nc, acnt = ncnt, aoff = noff, abase = nbase + 64;
        if (have_n && abase >= acnt) {
            ac = nc + GPERS; abase = 0;
            if (ac < CC) { acnt = counts[ac]; aoff = offsets[ac]; }
        }
        int midx_a = 0;
        if (have_n && ac < CC) midx_a = sorted_idx[aoff + min(abase + m0, acnt - 1)];

        // (3) MFMA current tile from lds[buf]
        f32x4 acc[4][2];
        #pragma unroll
        for (int ma = 0; ma < 4; ++ma)
            #pragma unroll
            for (int nb = 0; nb < 2; ++nb)
                acc[ma][nb] = (f32x4){0.f, 0.f, 0.f, 0.f};

        __builtin_amdgcn_s_setprio(1);
        #pragma unroll
        for (int kc = 0; kc < 8; ++kc) {
            bf16x8 a[4];
            int lx = (l ^ kc) << 4;    // chunk byte offset within fragment
            #pragma unroll
            for (int ma = 0; ma < 4; ++ma) {
                int byte = ((ma * 8 + kc) << 10) + lx;
                a[ma] = *(const bf16x8*)(&lds[buf][0] + byte);
            }
            #pragma unroll
            for (int ma = 0; ma < 4; ++ma)
                #pragma unroll
                for (int nb = 0; nb < 2; ++nb)
                    acc[ma][nb] = __builtin_amdgcn_mfma_f32_16x16x32_bf16(
                        a[ma], bfr[kc * 2 + nb], acc[ma][nb], 0, 0, 0);
        }
        __builtin_amdgcn_s_setprio(0);

        // (4) fold tile into running stats (padded rows are exact zeros -> sum safe)
        const bool last = (cbase + 64 >= ccnt);
        if (cbase + 64 <= ccnt) {
            #pragma unroll
            for (int ma = 0; ma < 4; ++ma)
                #pragma unroll
                for (int reg = 0; reg < 4; ++reg)
                    #pragma unroll
                    for (int nb = 0; nb < 2; ++nb) {
                        float v = acc[ma][nb][reg];
                        s_sum[nb] += v;
                        if (w < 4) {
                            s_max[nb] = fmaxf(s_max[nb], v);
                            s_min[nb] = fminf(s_min[nb], v);
                        }
                    }
        } else {
            int mb = cbase + 4 * (l >> 4);
            #pragma unroll
            for (int ma = 0; ma < 4; ++ma)
                #pragma unroll
                for (int reg = 0; reg < 4; ++reg) {
                    bool valid = (mb + 16 * ma + reg) < ccnt;
                    #pragma unroll
                    for (int nb = 0; nb < 2; ++nb) {
                        float v = acc[ma][nb][reg];
                        s_sum[nb] += v;
                        if (w < 4 && valid) {
                            s_max[nb] = fmaxf(s_max[nb], v);
                            s_min[nb] = fminf(s_min[nb], v);
                        }
                    }
                }
        }

        // class end: combine + write stats, reset
        if (last) {
            #pragma unroll
            for (int nb = 0; nb < 2; ++nb) {
                s_sum[nb] *= INVTEMP;
                s_sum[nb] += __shfl_xor(s_sum[nb], 16);
                s_sum[nb] += __shfl_xor(s_sum[nb], 32);
                if (w < 4) {
                    s_max[nb] *= INVTEMP;
                    s_min[nb] *= INVTEMP;
                    s_max[nb] = fmaxf(s_max[nb], __shfl_xor(s_max[nb], 16));
                    s_max[nb] = fmaxf(s_max[nb], __shfl_xor(s_max[nb], 32));
                    s_min[nb] = fminf(s_min[nb], __shfl_xor(s_min[nb], 16));
                    s_min[nb] = fminf(s_min[nb], __shfl_xor(s_min[nb], 32));
                }
            }
            if (l < 16) {
                #pragma unroll
                for (int nb = 0; nb < 2; ++nb) {
                    if (w < 4) {
                        int col = 32 * w + 16 * nb + l; // 0..127 (inputs)
                        gsumA[(size_t)col * CC + cc] = s_sum[nb];
                        gmax[(size_t)col * CC + cc]  = s_max[nb];
                        gmin[(size_t)col * CC + cc]  = s_min[nb];
                    } else {
                        int col = 32 * (w - 4) + 16 * nb + l; // 0..127 (inputs2)
                        gsumB[(size_t)col * CC + cc] = s_sum[nb];
                    }
                }
            }
            s_sum[0] = s_sum[1] = 0.f;
            s_max[0] = s_max[1] = -3.4e38f;
            s_min[0] = s_min[1] =  3.4e38f;
        }

        // (5) convert staged rows -> lds[buf^1]
        if (have_n) {
            #pragma unroll
            for (int hi = 0; hi < 4; ++hi) {
                u16x8 o = (u16x8)0;
                if (nrow_valid) {
                    float4 a = S[2 * hi], b = S[2 * hi + 1];
                    o[0] = f2bf(a.x); o[1] = f2bf(a.y); o[2] = f2bf(a.z); o[3] = f2bf(a.w);
                    o[4] = f2bf(b.x); o[5] = f2bf(b.y); o[6] = f2bf(b.z); o[7] = f2bf(b.w);
                }
                int byte = frag_base + ((((hi << 4) + chunk_lo)) << 4);
                *(u16x8*)(&lds[buf ^ 1][0] + byte) = o;
            }
        }
        __syncthreads();

        // (6) shift pipeline
        cc = nc; ccnt = ncnt; coff = noff; cbase = nbase;
        nc = ac; ncnt = acnt; noff = aoff; nbase = abase;
        midx_n = midx_a;
        buf ^= 1;
    }
}

// ---------------- finalize: losses ----------------

__device__ __forceinline__ float blk_reduce_sum(float v) {
    __shared__ float sh[4];
    int lane = threadIdx.x & 63, w = threadIdx.x >> 6;
    #pragma unroll
    for (int o = 32; o; o >>= 1) v += __shfl_down(v, o, 64);
    __syncthreads();
    if (lane == 0) sh[w] = v;
    __syncthreads();
    return sh[0] + sh[1] + sh[2] + sh[3];
}

__device__ __forceinline__ float blk_reduce_max(float v) {
    __shared__ float sh[4];
    int lane = threadIdx.x & 63, w = threadIdx.x >> 6;
    #pragma unroll
    for (int o = 32; o; o >>= 1) v = fmaxf(v, __shfl_down(v, o, 64));
    __syncthreads();
    if (lane == 0) sh[w] = v;
    __syncthreads();
    return fmaxf(fmaxf(sh[0], sh[1]), fmaxf(sh[2], sh[3]));
}

__global__ __launch_bounds__(256) void finalize_kernel(
    const float* __restrict__ gsumA, const float* __restrict__ gsumB,
    const float* __restrict__ gmax, const float* __restrict__ gmin,
    const int* __restrict__ counts, const int* __restrict__ labels,
    const int* __restrict__ indexes, float* __restrict__ out)
{
    const int b   = blockIdx.x;
    const int tid = threadIdx.x;
    const int tgt = labels[indexes[b]];

    __shared__ float sh_etgt;
    float local = 0.f;
    for (int c = tid; c < CC; c += 256) {
        float v = (c == tgt) ? gmin[(size_t)b * CC + c] : gmax[(size_t)b * CC + c];
        float e = (counts[c] > 0) ? expf(v) : 0.f;
        local += e;
        if (c == tgt) sh_etgt = e;
    }
    float sum_e = blk_reduce_sum(local);
    float etgt = sh_etgt;
    float loss_con_b = -logf(etgt / (sum_e + EPSV) + EPSV);

    __shared__ float a1[SS], a2[SS];
    for (int c = tid; c < SS; c += 256) {
        int n = counts[c];
        float icnt = 1.f / (float)(n > 0 ? n : 1);
        a1[c] = gsumA[(size_t)b * CC + c] * icnt;
        a2[c] = gsumB[(size_t)b * CC + c] * icnt;
    }
    __syncthreads();
    float m1 = -3.4e38f, m2 = -3.4e38f;
    for (int c = tid; c < SS; c += 256) { m1 = fmaxf(m1, a1[c]); m2 = fmaxf(m2, a2[c]); }
    m1 = blk_reduce_max(m1);
    m2 = blk_reduce_max(m2);
    float s1 = 0.f, s2 = 0.f;
    for (int c = tid; c < SS; c += 256) { s1 += expf(a1[c] - m1); s2 += expf(a2[c] - m2); }
    s1 = blk_reduce_sum(s1);
    s2 = blk_reduce_sum(s2);
    float inv1 = 1.f / s1, inv2 = 1.f / s2;
    float dsum = 0.f;
    for (int c = tid; c < SS; c += 256) {
        float d = expf(a1[c] - m1) * inv1 - expf(a2[c] - m2) * inv2;
        dsum += d * d;
    }
    dsum = blk_reduce_sum(dsum);
    if (tid == 0) {
        atomicAdd(&out[0], loss_con_b * (1.0f / (float)BB));
        atomicAdd(&out[1], dsum * (1.0f / (float)SS));
    }
}

// ---------------- launch ----------------

extern "C" void kernel_launch(void* const* d_in, const int* in_sizes, int n_in,
                              void* d_out, int out_size, void* d_ws, size_t ws_size,
                              hipStream_t stream) {
    const float* inputs   = (const float*)d_in[0];
    const float* inputs2  = (const float*)d_in[1];
    const float* features = (const float*)d_in[2];
    const int*   labels   = (const int*)d_in[3];
    const int*   indexes  = (const int*)d_in[4];

    float* out = (float*)d_out;

    // workspace layout
    int* wsi     = (int*)d_ws;
    int* counts  = wsi;            // 2048
    int* offsets = wsi + 2048;     // 2048
    int* cursor  = wsi + 4096;     // 2048
    int* sorted  = wsi + 6144;     // 100000
    unsigned short* inb = (unsigned short*)(wsi + 106144); // 65536 ushorts = 128 KB
    float* gsumA = (float*)d_ws + 138912;                  // [128][CC] each
    float* gsumB = gsumA + CC * BB;
    float* gmaxp = gsumB + CC * BB;
    float* gminp = gmaxp + CC * BB;

    hipMemsetAsync(counts, 0, 2048 * sizeof(int), stream);

    hist_prep_kernel<<<HIST_BLOCKS + PREP_BLOCKS, 256, 0, stream>>>(
        labels, counts, inputs, inputs2, inb);
    scan_kernel<<<1, 256, 0, stream>>>(counts, offsets, cursor, out);
    scatter_kernel<<<(NN + 255) / 256, 256, 0, stream>>>(labels, cursor, sorted);
    class_mfma<<<GPERS, 512, 0, stream>>>(features, inb, offsets, counts, sorted,
                                          gsumA, gsumB, gmaxp, gminp);
    finalize_kernel<<<BB, 256, 0, stream>>>(gsumA, gsumB, gmaxp, gminp, counts,
                                            labels, indexes, out);
}

// Round 6
// 122.018 us; speedup vs baseline: 1.2459x; 1.2459x over previous
//
#include <hip/hip_runtime.h>
#include <hip/hip_bf16.h>

// Problem constants
#define BB 128        // batch
#define NN 100000     // memory bank size
#define DD 256        // feature dim (K)
#define CC 2000       // num classes
#define SS 751        // source classes
#define INVTEMP 20.0f // 1/0.05
#define EPSV 1e-6f

#define HIST_BLOCKS 391   // ceil(100000/256)
#define PREP_BLOCKS 32    // 8192/256
#define GPERS 256         // persistent grid for class_mfma (1 big block/CU)

typedef __attribute__((ext_vector_type(8))) short bf16x8;   // 8 bf16 in 4 VGPRs
typedef __attribute__((ext_vector_type(8))) unsigned short u16x8;
typedef __attribute__((ext_vector_type(4))) float f32x4;

__device__ __forceinline__ unsigned short f2bf(float x) {
    unsigned int u = __float_as_uint(x);
    u += 0x7fffu + ((u >> 16) & 1u);   // round-to-nearest-even
    return (unsigned short)(u >> 16);
}

__device__ __forceinline__ u16x8 pack8(float4 a, float4 b) {
    u16x8 o;
    o[0] = f2bf(a.x); o[1] = f2bf(a.y); o[2] = f2bf(a.z); o[3] = f2bf(a.w);
    o[4] = f2bf(b.x); o[5] = f2bf(b.y); o[6] = f2bf(b.z); o[7] = f2bf(b.w);
    return o;
}

// ---------------- fused: histogram + input-fragment prep ----------------
// inb layout: 16B chunk ch = (nr*8 + kc)*64 + l holds
//   row = nr*16 + (l&15)  (rows 0..127 inputs, 128..255 inputs2)
//   k   = kc*32 + (l>>4)*8 + j, j=0..7
__global__ __launch_bounds__(256) void hist_prep_kernel(
    const int* __restrict__ labels, int* __restrict__ counts,
    const float* __restrict__ in1, const float* __restrict__ in2,
    unsigned short* __restrict__ inb)
{
    int bid = blockIdx.x;
    if (bid < HIST_BLOCKS) {
        int n = bid * 256 + threadIdx.x;
        if (n < NN) atomicAdd(&counts[labels[n]], 1);
    } else {
        int ch = (bid - HIST_BLOCKS) * 256 + threadIdx.x;
        if (ch >= 8192) return;
        int l  = ch & 63;
        int kc = (ch >> 6) & 7;
        int nr = ch >> 9;
        int row = nr * 16 + (l & 15);
        const float* src = (row < BB) ? (in1 + (size_t)row * DD)
                                      : (in2 + (size_t)(row - BB) * DD);
        int k0 = kc * 32 + ((l >> 4) << 3);
        u16x8 o;
        #pragma unroll
        for (int j = 0; j < 8; ++j) o[j] = f2bf(src[k0 + j]);
        *(u16x8*)(inb + (size_t)ch * 8) = o;
    }
}

// one block, 256 threads, exclusive scan over 2048 (padded) counts; also zeroes out
__global__ __launch_bounds__(256) void scan_kernel(const int* __restrict__ counts,
                                                   int* __restrict__ offsets,
                                                   int* __restrict__ cursor,
                                                   float* __restrict__ out) {
    const int PT = 8; // 256*8 = 2048 >= CC
    int tid = threadIdx.x;
    if (tid == 0) { out[0] = 0.f; out[1] = 0.f; }
    int vals[PT];
    int tot = 0;
    #pragma unroll
    for (int i = 0; i < PT; ++i) {
        int c = tid * PT + i;
        vals[i] = (c < CC) ? counts[c] : 0;
        tot += vals[i];
    }
    __shared__ int sh[256];
    sh[tid] = tot;
    __syncthreads();
    for (int ofs = 1; ofs < 256; ofs <<= 1) {
        int v = (tid >= ofs) ? sh[tid - ofs] : 0;
        __syncthreads();
        sh[tid] += v;
        __syncthreads();
    }
    int run = sh[tid] - tot;
    #pragma unroll
    for (int i = 0; i < PT; ++i) {
        int c = tid * PT + i;
        if (c < CC) { offsets[c] = run; cursor[c] = run; }
        run += vals[i];
    }
}

__global__ void scatter_kernel(const int* __restrict__ labels, int* __restrict__ cursor,
                               int* __restrict__ sorted_idx) {
    int n = blockIdx.x * 256 + threadIdx.x;
    if (n < NN) {
        int c = labels[n];
        int p = atomicAdd(&cursor[c], 1);
        sorted_idx[p] = n;
    }
}

// ---------------- heavy kernel: persistent, 1024 threads, square wave-tiles ----------------
// Grid = GPERS blocks x 1024 threads (16 waves). Block walks classes c = bid, bid+GPERS, ...
// Wave w: mb = w&1 (member half: rows 32*mb..+32), cb = w>>1 (col block: cols 32*cb..+32;
// cb<4 -> inputs [sum+max+min], cb>=4 -> inputs2 [sum]).
// Per-wave tile = 32 members x 32 cols: A reads 16KB/tile (2 ma x 8 kc ds_read_b128),
// B = 16 hoisted fragments (64 VGPR), acc = 2x2 f32x4 (16 regs). Total ~120 regs ->
// 4 waves/SIMD, no spill.
// LDS A-tile in FRAGMENT ORDER (conflict-free, verified r5): fragment (MA,kc) = 1KB,
// lane l's chunk at (l^kc). Staging (1024 thr): thread = (row m0=tid>>4, seg s=tid&15),
// loads 16 f32, writes 2 chunks; quad spread uniform 8 lanes -> conflict-free.
// Pipeline depth 2: gather t+1 while MFMAing t. Member halves combined at class end
// via small LDS buffer (block-uniform barrier).
__global__ __launch_bounds__(1024, 4) void class_mfma(
    const float* __restrict__ features, const unsigned short* __restrict__ inb,
    const int* __restrict__ offsets, const int* __restrict__ counts,
    const int* __restrict__ sorted_idx,
    float* __restrict__ gsumA, float* __restrict__ gsumB,
    float* __restrict__ gmax, float* __restrict__ gmin)
{
    const int tid = threadIdx.x;
    const int w   = tid >> 6;
    const int l   = tid & 63;
    const int mb  = w & 1;     // member half
    const int cb  = w >> 1;    // col block 0..7
    const int m0  = tid >> 4;  // staging: member row 0..63
    const int sg  = tid & 15;  // staging: 16-f32 segment of the row

    __shared__ __align__(16) char lds[2][32768];   // double-buffered A tile (fragment order)
    __shared__ float comb_s[8][2][16];             // class-end cross-wave combine buffers
    __shared__ float comb_mx[4][2][16];
    __shared__ float comb_mn[4][2][16];

    // hoist B (input) fragments: kc 0..7, nb 0..1 -> 16 x bf16x8 (64 VGPR)
    bf16x8 bfr[16];
    #pragma unroll
    for (int kc = 0; kc < 8; ++kc)
        #pragma unroll
        for (int nb = 0; nb < 2; ++nb) {
            int nr = 2 * cb + nb;
            bfr[kc * 2 + nb] = *(const bf16x8*)(inb + (((size_t)(nr * 8 + kc) * 64 + l) << 3));
        }

    // staging address constants: kc = sg>>1, octet pair o0 = 2*(sg&1)
    const int st_kc   = sg >> 1;
    const int st_byte = (((m0 >> 4) * 8 + st_kc) << 10)                      // fragment (m0>>4, kc)
                      + ((((2 * (sg & 1)) << 4) | ((m0 & 15) ^ st_kc)) << 4); // chunk (o0, row^kc)

    // ---- tile iterator state (block-uniform) ----
    int cc = blockIdx.x;
    int ccnt = counts[cc], coff = offsets[cc];
    int cbase = 0;

    int nc = cc, ncnt = ccnt, noff = coff, nbase = 64; // next tile
    if (nbase >= ncnt) {
        nc = cc + GPERS; nbase = 0;
        if (nc < CC) { ncnt = counts[nc]; noff = offsets[nc]; }
    }

    // ---- prologue: stage tile 0 into lds[0] ----
    {
        int n0  = sorted_idx[coff + min(m0, ccnt - 1)];
        bool v0 = m0 < ccnt;
        const float4* src = (const float4*)(features + (size_t)n0 * DD) + sg * 4;
        float4 S0 = src[0], S1 = src[1], S2 = src[2], S3 = src[3];
        u16x8 o0 = (u16x8)0, o1 = (u16x8)0;
        if (v0) { o0 = pack8(S0, S1); o1 = pack8(S2, S3); }
        *(u16x8*)(&lds[0][0] + st_byte) = o0;
        *(u16x8*)(&lds[0][0] + st_byte + 256) = o1;
    }
    int midx_n = 0;
    if (nc < CC) midx_n = sorted_idx[noff + min(nbase + m0, ncnt - 1)];
    __syncthreads();

    float s_sum[2] = {0.f, 0.f};
    float s_max[2] = {-3.4e38f, -3.4e38f};
    float s_min[2] = { 3.4e38f,  3.4e38f};

    int buf = 0;

    while (cc < CC) {
        const bool have_n = (nc < CC);

        // (1) issue gather for next tile
        float4 S0, S1, S2, S3;
        if (have_n) {
            const float4* src = (const float4*)(features + (size_t)midx_n * DD) + sg * 4;
            S0 = src[0]; S1 = src[1]; S2 = src[2]; S3 = src[3];
        }
        const bool nrow_valid = have_n && (nbase + m0 < ncnt);

        // (2) advance to after-next tile; prefetch its midx
        int ac = nc, acnt = ncnt, aoff = noff, abase = nbase + 64;
        if (have_n && abase >= acnt) {
            ac = nc + GPERS; abase = 0;
            if (ac < CC) { acnt = counts[ac]; aoff = offsets[ac]; }
        }
        int midx_a = 0;
        if (have_n && ac < CC) midx_a = sorted_idx[aoff + min(abase + m0, acnt - 1)];

        // (3) MFMA current tile from lds[buf]: 2 ma x 2 nb x 8 kc
        f32x4 acc[2][2];
        #pragma unroll
        for (int ma = 0; ma < 2; ++ma)
            #pragma unroll
            for (int nb = 0; nb < 2; ++nb)
                acc[ma][nb] = (f32x4){0.f, 0.f, 0.f, 0.f};

        __builtin_amdgcn_s_setprio(1);
        #pragma unroll
        for (int kc = 0; kc < 8; ++kc) {
            bf16x8 a[2];
            int lx = (l ^ kc) << 4;
            #pragma unroll
            for (int ma = 0; ma < 2; ++ma) {
                int byte = (((2 * mb + ma) * 8 + kc) << 10) + lx;
                a[ma] = *(const bf16x8*)(&lds[buf][0] + byte);
            }
            #pragma unroll
            for (int ma = 0; ma < 2; ++ma)
                #pragma unroll
                for (int nb = 0; nb < 2; ++nb)
                    acc[ma][nb] = __builtin_amdgcn_mfma_f32_16x16x32_bf16(
                        a[ma], bfr[kc * 2 + nb], acc[ma][nb], 0, 0, 0);
        }
        __builtin_amdgcn_s_setprio(0);

        // (4) fold tile into running stats (padded rows are exact zeros -> sum safe)
        const bool last = (cbase + 64 >= ccnt);
        const bool do_mm = (cb < 4);
        if (cbase + 64 <= ccnt) {
            #pragma unroll
            for (int ma = 0; ma < 2; ++ma)
                #pragma unroll
                for (int reg = 0; reg < 4; ++reg)
                    #pragma unroll
                    for (int nb = 0; nb < 2; ++nb) {
                        float v = acc[ma][nb][reg];
                        s_sum[nb] += v;
                        if (do_mm) {
                            s_max[nb] = fmaxf(s_max[nb], v);
                            s_min[nb] = fminf(s_min[nb], v);
                        }
                    }
        } else {
            int mrow = cbase + 32 * mb + 4 * (l >> 4);
            #pragma unroll
            for (int ma = 0; ma < 2; ++ma)
                #pragma unroll
                for (int reg = 0; reg < 4; ++reg) {
                    bool valid = (mrow + 16 * ma + reg) < ccnt;
                    #pragma unroll
                    for (int nb = 0; nb < 2; ++nb) {
                        float v = acc[ma][nb][reg];
                        s_sum[nb] += v;
                        if (do_mm && valid) {
                            s_max[nb] = fmaxf(s_max[nb], v);
                            s_min[nb] = fminf(s_min[nb], v);
                        }
                    }
                }
        }

        // class end: in-wave reduce, cross-wave (member-half) combine, write stats
        if (last) {
            #pragma unroll
            for (int nb = 0; nb < 2; ++nb) {
                s_sum[nb] += __shfl_xor(s_sum[nb], 16);
                s_sum[nb] += __shfl_xor(s_sum[nb], 32);
                if (do_mm) {
                    s_max[nb] = fmaxf(s_max[nb], __shfl_xor(s_max[nb], 16));
                    s_max[nb] = fmaxf(s_max[nb], __shfl_xor(s_max[nb], 32));
                    s_min[nb] = fminf(s_min[nb], __shfl_xor(s_min[nb], 16));
                    s_min[nb] = fminf(s_min[nb], __shfl_xor(s_min[nb], 32));
                }
            }
            if (mb == 1 && l < 16) {
                #pragma unroll
                for (int nb = 0; nb < 2; ++nb) {
                    comb_s[cb][nb][l] = s_sum[nb];
                    if (do_mm) {
                        comb_mx[cb][nb][l] = s_max[nb];
                        comb_mn[cb][nb][l] = s_min[nb];
                    }
                }
            }
            __syncthreads();
            if (mb == 0 && l < 16) {
                #pragma unroll
                for (int nb = 0; nb < 2; ++nb) {
                    float tsum = (s_sum[nb] + comb_s[cb][nb][l]) * INVTEMP;
                    if (do_mm) {
                        int col = 32 * cb + 16 * nb + l;
                        float tmax = fmaxf(s_max[nb], comb_mx[cb][nb][l]) * INVTEMP;
                        float tmin = fminf(s_min[nb], comb_mn[cb][nb][l]) * INVTEMP;
                        gsumA[(size_t)col * CC + cc] = tsum;
                        gmax[(size_t)col * CC + cc]  = tmax;
                        gmin[(size_t)col * CC + cc]  = tmin;
                    } else {
                        int col = 32 * (cb - 4) + 16 * nb + l;
                        gsumB[(size_t)col * CC + cc] = tsum;
                    }
                }
            }
            s_sum[0] = s_sum[1] = 0.f;
            s_max[0] = s_max[1] = -3.4e38f;
            s_min[0] = s_min[1] =  3.4e38f;
        }

        // (5) convert staged rows -> lds[buf^1]
        if (have_n) {
            u16x8 o0 = (u16x8)0, o1 = (u16x8)0;
            if (nrow_valid) { o0 = pack8(S0, S1); o1 = pack8(S2, S3); }
            *(u16x8*)(&lds[buf ^ 1][0] + st_byte) = o0;
            *(u16x8*)(&lds[buf ^ 1][0] + st_byte + 256) = o1;
        }
        __syncthreads();

        // (6) shift pipeline
        cc = nc; ccnt = ncnt; coff = noff; cbase = nbase;
        nc = ac; ncnt = acnt; noff = aoff; nbase = abase;
        midx_n = midx_a;
        buf ^= 1;
    }
}

// ---------------- finalize: losses ----------------

__device__ __forceinline__ float blk_reduce_sum(float v) {
    __shared__ float sh[4];
    int lane = threadIdx.x & 63, w = threadIdx.x >> 6;
    #pragma unroll
    for (int o = 32; o; o >>= 1) v += __shfl_down(v, o, 64);
    __syncthreads();
    if (lane == 0) sh[w] = v;
    __syncthreads();
    return sh[0] + sh[1] + sh[2] + sh[3];
}

__device__ __forceinline__ float blk_reduce_max(float v) {
    __shared__ float sh[4];
    int lane = threadIdx.x & 63, w = threadIdx.x >> 6;
    #pragma unroll
    for (int o = 32; o; o >>= 1) v = fmaxf(v, __shfl_down(v, o, 64));
    __syncthreads();
    if (lane == 0) sh[w] = v;
    __syncthreads();
    return fmaxf(fmaxf(sh[0], sh[1]), fmaxf(sh[2], sh[3]));
}

__global__ __launch_bounds__(256) void finalize_kernel(
    const float* __restrict__ gsumA, const float* __restrict__ gsumB,
    const float* __restrict__ gmax, const float* __restrict__ gmin,
    const int* __restrict__ counts, const int* __restrict__ labels,
    const int* __restrict__ indexes, float* __restrict__ out)
{
    const int b   = blockIdx.x;
    const int tid = threadIdx.x;
    const int tgt = labels[indexes[b]];

    __shared__ float sh_etgt;
    float local = 0.f;
    for (int c = tid; c < CC; c += 256) {
        float v = (c == tgt) ? gmin[(size_t)b * CC + c] : gmax[(size_t)b * CC + c];
        float e = (counts[c] > 0) ? expf(v) : 0.f;
        local += e;
        if (c == tgt) sh_etgt = e;
    }
    float sum_e = blk_reduce_sum(local);
    float etgt = sh_etgt;
    float loss_con_b = -logf(etgt / (sum_e + EPSV) + EPSV);

    __shared__ float a1[SS], a2[SS];
    for (int c = tid; c < SS; c += 256) {
        int n = counts[c];
        float icnt = 1.f / (float)(n > 0 ? n : 1);
        a1[c] = gsumA[(size_t)b * CC + c] * icnt;
        a2[c] = gsumB[(size_t)b * CC + c] * icnt;
    }
    __syncthreads();
    float m1 = -3.4e38f, m2 = -3.4e38f;
    for (int c = tid; c < SS; c += 256) { m1 = fmaxf(m1, a1[c]); m2 = fmaxf(m2, a2[c]); }
    m1 = blk_reduce_max(m1);
    m2 = blk_reduce_max(m2);
    float s1 = 0.f, s2 = 0.f;
    for (int c = tid; c < SS; c += 256) { s1 += expf(a1[c] - m1); s2 += expf(a2[c] - m2); }
    s1 = blk_reduce_sum(s1);
    s2 = blk_reduce_sum(s2);
    float inv1 = 1.f / s1, inv2 = 1.f / s2;
    float dsum = 0.f;
    for (int c = tid; c < SS; c += 256) {
        float d = expf(a1[c] - m1) * inv1 - expf(a2[c] - m2) * inv2;
        dsum += d * d;
    }
    dsum = blk_reduce_sum(dsum);
    if (tid == 0) {
        atomicAdd(&out[0], loss_con_b * (1.0f / (float)BB));
        atomicAdd(&out[1], dsum * (1.0f / (float)SS));
    }
}

// ---------------- launch ----------------

extern "C" void kernel_launch(void* const* d_in, const int* in_sizes, int n_in,
                              void* d_out, int out_size, void* d_ws, size_t ws_size,
                              hipStream_t stream) {
    const float* inputs   = (const float*)d_in[0];
    const float* inputs2  = (const float*)d_in[1];
    const float* features = (const float*)d_in[2];
    const int*   labels   = (const int*)d_in[3];
    const int*   indexes  = (const int*)d_in[4];

    float* out = (float*)d_out;

    // workspace layout
    int* wsi     = (int*)d_ws;
    int* counts  = wsi;            // 2048
    int* offsets = wsi + 2048;     // 2048
    int* cursor  = wsi + 4096;     // 2048
    int* sorted  = wsi + 6144;     // 100000
    unsigned short* inb = (unsigned short*)(wsi + 106144); // 65536 ushorts = 128 KB
    float* gsumA = (float*)d_ws + 138912;                  // [128][CC] each
    float* gsumB = gsumA + CC * BB;
    float* gmaxp = gsumB + CC * BB;
    float* gminp = gmaxp + CC * BB;

    hipMemsetAsync(counts, 0, 2048 * sizeof(int), stream);

    hist_prep_kernel<<<HIST_BLOCKS + PREP_BLOCKS, 256, 0, stream>>>(
        labels, counts, inputs, inputs2, inb);
    scan_kernel<<<1, 256, 0, stream>>>(counts, offsets, cursor, out);
    scatter_kernel<<<(NN + 255) / 256, 256, 0, stream>>>(labels, cursor, sorted);
    class_mfma<<<GPERS, 1024, 0, stream>>>(features, inb, offsets, counts, sorted,
                                           gsumA, gsumB, gmaxp, gminp);
    finalize_kernel<<<BB, 256, 0, stream>>>(gsumA, gsumB, gmaxp, gminp, counts,
                                            labels, indexes, out);
}

// Round 7
// 102.453 us; speedup vs baseline: 1.4839x; 1.1910x over previous
//
#include <hip/hip_runtime.h>
#include <hip/hip_bf16.h>

// Problem constants
#define BB 128        // batch
#define NN 100000     // memory bank size
#define DD 256        // feat dim (K)
#define CC 2000       // num classes
#define SS 751        // source classes
#define INVTEMP 20.0f // 1/0.05
#define EPSV 1e-6f

#define HIST_BLOCKS 391   // ceil(100000/256)
#define PREP_BLOCKS 32    // 8192/256
#define GPERS 512         // persistent grid: 2 blocks/CU co-resident

typedef __attribute__((ext_vector_type(8))) short bf16x8;   // 8 bf16 in 4 VGPRs
typedef __attribute__((ext_vector_type(8))) unsigned short u16x8;
typedef __attribute__((ext_vector_type(4))) float f32x4;

__device__ __forceinline__ unsigned short f2bf(float x) {
    unsigned int u = __float_as_uint(x);
    u += 0x7fffu + ((u >> 16) & 1u);   // round-to-nearest-even
    return (unsigned short)(u >> 16);
}

// ---------------- fused: histogram + input-fragment prep ----------------
// inb layout: 16B chunk ch = (nr*8 + kc)*64 + l holds
//   row = nr*16 + (l&15)  (rows 0..127 inputs, 128..255 inputs2)
//   k   = kc*32 + (l>>4)*8 + j, j=0..7
__global__ __launch_bounds__(256) void hist_prep_kernel(
    const int* __restrict__ labels, int* __restrict__ counts,
    const float* __restrict__ in1, const float* __restrict__ in2,
    unsigned short* __restrict__ inb)
{
    int bid = blockIdx.x;
    if (bid < HIST_BLOCKS) {
        int n = bid * 256 + threadIdx.x;
        if (n < NN) atomicAdd(&counts[labels[n]], 1);
    } else {
        int ch = (bid - HIST_BLOCKS) * 256 + threadIdx.x;
        if (ch >= 8192) return;
        int l  = ch & 63;
        int kc = (ch >> 6) & 7;
        int nr = ch >> 9;
        int row = nr * 16 + (l & 15);
        const float* src = (row < BB) ? (in1 + (size_t)row * DD)
                                      : (in2 + (size_t)(row - BB) * DD);
        int k0 = kc * 32 + ((l >> 4) << 3);
        u16x8 o;
        #pragma unroll
        for (int j = 0; j < 8; ++j) o[j] = f2bf(src[k0 + j]);
        *(u16x8*)(inb + (size_t)ch * 8) = o;
    }
}

// one block, 256 threads, exclusive scan over 2048 (padded) counts; also zeroes out
__global__ __launch_bounds__(256) void scan_kernel(const int* __restrict__ counts,
                                                   int* __restrict__ offsets,
                                                   int* __restrict__ cursor,
                                                   float* __restrict__ out) {
    const int PT = 8; // 256*8 = 2048 >= CC
    int tid = threadIdx.x;
    if (tid == 0) { out[0] = 0.f; out[1] = 0.f; }
    int vals[PT];
    int tot = 0;
    #pragma unroll
    for (int i = 0; i < PT; ++i) {
        int c = tid * PT + i;
        vals[i] = (c < CC) ? counts[c] : 0;
        tot += vals[i];
    }
    __shared__ int sh[256];
    sh[tid] = tot;
    __syncthreads();
    for (int ofs = 1; ofs < 256; ofs <<= 1) {
        int v = (tid >= ofs) ? sh[tid - ofs] : 0;
        __syncthreads();
        sh[tid] += v;
        __syncthreads();
    }
    int run = sh[tid] - tot;
    #pragma unroll
    for (int i = 0; i < PT; ++i) {
        int c = tid * PT + i;
        if (c < CC) { offsets[c] = run; cursor[c] = run; }
        run += vals[i];
    }
}

__global__ void scatter_kernel(const int* __restrict__ labels, int* __restrict__ cursor,
                               int* __restrict__ sorted_idx) {
    int n = blockIdx.x * 256 + threadIdx.x;
    if (n < NN) {
        int c = labels[n];
        int p = atomicAdd(&cursor[c], 1);
        sorted_idx[p] = n;
    }
}

// ---------------- heavy kernel: persistent, software-pipelined, 2 blocks/CU ----------------
// Grid = GPERS blocks x 512 threads (8 waves). Block walks classes c = bid, bid+GPERS, ...
// launch_bounds(512,2): compiler targets ~124 regs (r4-verified, NO spill); at 124 regs
// the HW fits 4 waves/SIMD -> 2 blocks/CU co-resident (grid now large enough).
// LDS A-tile in FRAGMENT ORDER (r5-verified: 0 bank conflicts): fragment (ma,kc) =
// contiguous 1KB; lane l's 16B at chunk l^kc. Write side (thread = row m0, k-col s8):
// chunk (hi*16+((m0&15)^s8)) of fragment (m0>>4, s8) -> uniform bank spread.
// Pipeline depth 2: gather t+1 into regs while MFMAing t; write LDS after fold;
// one barrier per tile. Wave w: batch cols [32w,+32) (w<4 inputs: sum+max+min;
// w>=4 inputs2: sum). Stats transposed [col][CC] for coalesced finalize.
__global__ __launch_bounds__(512, 2) void class_mfma(
    const float* __restrict__ features, const unsigned short* __restrict__ inb,
    const int* __restrict__ offsets, const int* __restrict__ counts,
    const int* __restrict__ sorted_idx,
    float* __restrict__ gsumA, float* __restrict__ gsumB,
    float* __restrict__ gmax, float* __restrict__ gmin)
{
    const int tid = threadIdx.x;
    const int w   = tid >> 6;
    const int l   = tid & 63;
    const int m0  = tid >> 3;  // staging: member row 0..63
    const int s8  = tid & 7;   // staging: 128B f32 segment (= fragment k-column)

    __shared__ __align__(16) char lds[2][32768]; // double-buffered A tile (bf16, fragment order)

    // hoist B (input) fragments: kc 0..7, nb 0..1 -> 16 x bf16x8 (64 VGPR)
    bf16x8 bfr[16];
    #pragma unroll
    for (int kc = 0; kc < 8; ++kc)
        #pragma unroll
        for (int nb = 0; nb < 2; ++nb) {
            int nr = 2 * w + nb;
            bfr[kc * 2 + nb] = *(const bf16x8*)(inb + (((size_t)(nr * 8 + kc) * 64 + l) << 3));
        }

    // staging address constants
    const int frag_base = (((m0 >> 4) * 8 + s8) << 10);   // fragment (m0>>4, s8)
    const int chunk_lo  = (m0 & 15) ^ s8;                  // low 4 bits of chunk

    // ---- tile iterator state (all wave-uniform) ----
    int cc = blockIdx.x;               // current class
    int ccnt = counts[cc], coff = offsets[cc];
    int cbase = 0;

    int nc = cc, ncnt = ccnt, noff = coff, nbase = 64; // next tile
    if (nbase >= ncnt) {
        nc = cc + GPERS; nbase = 0;
        if (nc < CC) { ncnt = counts[nc]; noff = offsets[nc]; }
    }

    // ---- prologue: stage tile 0 into lds[0] ----
    {
        int idx = coff + min(cbase + m0, ccnt - 1);
        int n0  = sorted_idx[idx];
        bool v0 = (cbase + m0) < ccnt;
        const float4* src = (const float4*)(features + (size_t)n0 * DD) + s8 * 8;
        float4 S[8];
        #pragma unroll
        for (int j = 0; j < 8; ++j) S[j] = src[j];
        #pragma unroll
        for (int hi = 0; hi < 4; ++hi) {
            u16x8 o = (u16x8)0;
            if (v0) {
                float4 a = S[2 * hi], b = S[2 * hi + 1];
                o[0] = f2bf(a.x); o[1] = f2bf(a.y); o[2] = f2bf(a.z); o[3] = f2bf(a.w);
                o[4] = f2bf(b.x); o[5] = f2bf(b.y); o[6] = f2bf(b.z); o[7] = f2bf(b.w);
            }
            int byte = frag_base + ((((hi << 4) + chunk_lo)) << 4);
            *(u16x8*)(&lds[0][0] + byte) = o;
        }
    }
    // prefetch midx for next tile
    int midx_n = 0;
    if (nc < CC) midx_n = sorted_idx[noff + min(nbase + m0, ncnt - 1)];
    __syncthreads();

    float s_sum[2] = {0.f, 0.f};
    float s_max[2] = {-3.4e38f, -3.4e38f};
    float s_min[2] = { 3.4e38f,  3.4e38f};

    int buf = 0;

    while (cc < CC) {
        const bool have_n = (nc < CC);

        // (1) issue gather for next tile (midx_n already resident)
        float4 S[8];
        if (have_n) {
            const float4* src = (const float4*)(features + (size_t)midx_n * DD) + s8 * 8;
            #pragma unroll
            for (int j = 0; j < 8; ++j) S[j] = src[j];
        }
        const bool nrow_valid = have_n && (nbase + m0 < ncnt);

        // (2) advance to after-next tile; prefetch its midx
        int ac = nc, acnt = ncnt, aoff = noff, abase = nbase + 64;
        if (have_n && abase >= acnt) {
            ac = nc + GPERS; abase = 0;
            if (ac < CC) { acnt = counts[ac]; aoff = offsets[ac]; }
        }
        int midx_a = 0;
        if (have_n && ac < CC) midx_a = sorted_idx[aoff + min(abase + m0, acnt - 1)];

        // (3) MFMA current tile from lds[buf]
        f32x4 acc[4][2];
        #pragma unroll
        for (int ma = 0; ma < 4; ++ma)
            #pragma unroll
            for (int nb = 0; nb < 2; ++nb)
                acc[ma][nb] = (f32x4){0.f, 0.f, 0.f, 0.f};

        __builtin_amdgcn_s_setprio(1);
        #pragma unroll
        for (int kc = 0; kc < 8; ++kc) {
            bf16x8 a[4];
            int lx = (l ^ kc) << 4;    // chunk byte offset within fragment
            #pragma unroll
            for (int ma = 0; ma < 4; ++ma) {
                int byte = ((ma * 8 + kc) << 10) + lx;
                a[ma] = *(const bf16x8*)(&lds[buf][0] + byte);
            }
            #pragma unroll
            for (int ma = 0; ma < 4; ++ma)
                #pragma unroll
                for (int nb = 0; nb < 2; ++nb)
                    acc[ma][nb] = __builtin_amdgcn_mfma_f32_16x16x32_bf16(
                        a[ma], bfr[kc * 2 + nb], acc[ma][nb], 0, 0, 0);
        }
        __builtin_amdgcn_s_setprio(0);

        // (4) fold tile into running stats (padded rows are exact zeros -> sum safe)
        const bool last = (cbase + 64 >= ccnt);
        if (cbase + 64 <= ccnt) {
            #pragma unroll
            for (int ma = 0; ma < 4; ++ma)
                #pragma unroll
                for (int reg = 0; reg < 4; ++reg)
                    #pragma unroll
                    for (int nb = 0; nb < 2; ++nb) {
                        float v = acc[ma][nb][reg];
                        s_sum[nb] += v;
                        if (w < 4) {
                            s_max[nb] = fmaxf(s_max[nb], v);
                            s_min[nb] = fminf(s_min[nb], v);
                        }
                    }
        } else {
            int mb = cbase + 4 * (l >> 4);
            #pragma unroll
            for (int ma = 0; ma < 4; ++ma)
                #pragma unroll
                for (int reg = 0; reg < 4; ++reg) {
                    bool valid = (mb + 16 * ma + reg) < ccnt;
                    #pragma unroll
                    for (int nb = 0; nb < 2; ++nb) {
                        float v = acc[ma][nb][reg];
                        s_sum[nb] += v;
                        if (w < 4 && valid) {
                            s_max[nb] = fmaxf(s_max[nb], v);
                            s_min[nb] = fminf(s_min[nb], v);
                        }
                    }
                }
        }

        // class end: combine + write stats, reset
        if (last) {
            #pragma unroll
            for (int nb = 0; nb < 2; ++nb) {
                s_sum[nb] *= INVTEMP;
                s_sum[nb] += __shfl_xor(s_sum[nb], 16);
                s_sum[nb] += __shfl_xor(s_sum[nb], 32);
                if (w < 4) {
                    s_max[nb] *= INVTEMP;
                    s_min[nb] *= INVTEMP;
                    s_max[nb] = fmaxf(s_max[nb], __shfl_xor(s_max[nb], 16));
                    s_max[nb] = fmaxf(s_max[nb], __shfl_xor(s_max[nb], 32));
                    s_min[nb] = fminf(s_min[nb], __shfl_xor(s_min[nb], 16));
                    s_min[nb] = fminf(s_min[nb], __shfl_xor(s_min[nb], 32));
                }
            }
            if (l < 16) {
                #pragma unroll
                for (int nb = 0; nb < 2; ++nb) {
                    if (w < 4) {
                        int col = 32 * w + 16 * nb + l; // 0..127 (inputs)
                        gsumA[(size_t)col * CC + cc] = s_sum[nb];
                        gmax[(size_t)col * CC + cc]  = s_max[nb];
                        gmin[(size_t)col * CC + cc]  = s_min[nb];
                    } else {
                        int col = 32 * (w - 4) + 16 * nb + l; // 0..127 (inputs2)
                        gsumB[(size_t)col * CC + cc] = s_sum[nb];
                    }
                }
            }
            s_sum[0] = s_sum[1] = 0.f;
            s_max[0] = s_max[1] = -3.4e38f;
            s_min[0] = s_min[1] =  3.4e38f;
        }

        // (5) convert staged rows -> lds[buf^1]
        if (have_n) {
            #pragma unroll
            for (int hi = 0; hi < 4; ++hi) {
                u16x8 o = (u16x8)0;
                if (nrow_valid) {
                    float4 a = S[2 * hi], b = S[2 * hi + 1];
                    o[0] = f2bf(a.x); o[1] = f2bf(a.y); o[2] = f2bf(a.z); o[3] = f2bf(a.w);
                    o[4] = f2bf(b.x); o[5] = f2bf(b.y); o[6] = f2bf(b.z); o[7] = f2bf(b.w);
                }
                int byte = frag_base + ((((hi << 4) + chunk_lo)) << 4);
                *(u16x8*)(&lds[buf ^ 1][0] + byte) = o;
            }
        }
        __syncthreads();

        // (6) shift pipeline
        cc = nc; ccnt = ncnt; coff = noff; cbase = nbase;
        nc = ac; ncnt = acnt; noff = aoff; nbase = abase;
        midx_n = midx_a;
        buf ^= 1;
    }
}

// ---------------- finalize: losses ----------------

__device__ __forceinline__ float blk_reduce_sum(float v) {
    __shared__ float sh[4];
    int lane = threadIdx.x & 63, w = threadIdx.x >> 6;
    #pragma unroll
    for (int o = 32; o; o >>= 1) v += __shfl_down(v, o, 64);
    __syncthreads();
    if (lane == 0) sh[w] = v;
    __syncthreads();
    return sh[0] + sh[1] + sh[2] + sh[3];
}

__device__ __forceinline__ float blk_reduce_max(float v) {
    __shared__ float sh[4];
    int lane = threadIdx.x & 63, w = threadIdx.x >> 6;
    #pragma unroll
    for (int o = 32; o; o >>= 1) v = fmaxf(v, __shfl_down(v, o, 64));
    __syncthreads();
    if (lane == 0) sh[w] = v;
    __syncthreads();
    return fmaxf(fmaxf(sh[0], sh[1]), fmaxf(sh[2], sh[3]));
}

__global__ __launch_bounds__(256) void finalize_kernel(
    const float* __restrict__ gsumA, const float* __restrict__ gsumB,
    const float* __restrict__ gmax, const float* __restrict__ gmin,
    const int* __restrict__ counts, const int* __restrict__ labels,
    const int* __restrict__ indexes, float* __restrict__ out)
{
    const int b   = blockIdx.x;
    const int tid = threadIdx.x;
    const int tgt = labels[indexes[b]];

    __shared__ float sh_etgt;
    float local = 0.f;
    for (int c = tid; c < CC; c += 256) {
        float v = (c == tgt) ? gmin[(size_t)b * CC + c] : gmax[(size_t)b * CC + c];
        float e = (counts[c] > 0) ? expf(v) : 0.f;
        local += e;
        if (c == tgt) sh_etgt = e;
    }
    float sum_e = blk_reduce_sum(local);
    float etgt = sh_etgt;
    float loss_con_b = -logf(etgt / (sum_e + EPSV) + EPSV);

    __shared__ float a1[SS], a2[SS];
    for (int c = tid; c < SS; c += 256) {
        int n = counts[c];
        float icnt = 1.f / (float)(n > 0 ? n : 1);
        a1[c] = gsumA[(size_t)b * CC + c] * icnt;
        a2[c] = gsumB[(size_t)b * CC + c] * icnt;
    }
    __syncthreads();
    float m1 = -3.4e38f, m2 = -3.4e38f;
    for (int c = tid; c < SS; c += 256) { m1 = fmaxf(m1, a1[c]); m2 = fmaxf(m2, a2[c]); }
    m1 = blk_reduce_max(m1);
    m2 = blk_reduce_max(m2);
    float s1 = 0.f, s2 = 0.f;
    for (int c = tid; c < SS; c += 256) { s1 += expf(a1[c] - m1); s2 += expf(a2[c] - m2); }
    s1 = blk_reduce_sum(s1);
    s2 = blk_reduce_sum(s2);
    float inv1 = 1.f / s1, inv2 = 1.f / s2;
    float dsum = 0.f;
    for (int c = tid; c < SS; c += 256) {
        float d = expf(a1[c] - m1) * inv1 - expf(a2[c] - m2) * inv2;
        dsum += d * d;
    }
    dsum = blk_reduce_sum(dsum);
    if (tid == 0) {
        atomicAdd(&out[0], loss_con_b * (1.0f / (float)BB));
        atomicAdd(&out[1], dsum * (1.0f / (float)SS));
    }
}

// ---------------- launch ----------------

extern "C" void kernel_launch(void* const* d_in, const int* in_sizes, int n_in,
                              void* d_out, int out_size, void* d_ws, size_t ws_size,
                              hipStream_t stream) {
    const float* inputs   = (const float*)d_in[0];
    const float* inputs2  = (const float*)d_in[1];
    const float* features = (const float*)d_in[2];
    const int*   labels   = (const int*)d_in[3];
    const int*   indexes  = (const int*)d_in[4];

    float* out = (float*)d_out;

    // workspace layout
    int* wsi     = (int*)d_ws;
    int* counts  = wsi;            // 2048
    int* offsets = wsi + 2048;     // 2048
    int* cursor  = wsi + 4096;     // 2048
    int* sorted  = wsi + 6144;     // 100000
    unsigned short* inb = (unsigned short*)(wsi + 106144); // 65536 ushorts = 128 KB
    float* gsumA = (float*)d_ws + 138912;                  // [128][CC] each
    float* gsumB = gsumA + CC * BB;
    float* gmaxp = gsumB + CC * BB;
    float* gminp = gmaxp + CC * BB;

    hipMemsetAsync(counts, 0, 2048 * sizeof(int), stream);

    hist_prep_kernel<<<HIST_BLOCKS + PREP_BLOCKS, 256, 0, stream>>>(
        labels, counts, inputs, inputs2, inb);
    scan_kernel<<<1, 256, 0, stream>>>(counts, offsets, cursor, out);
    scatter_kernel<<<(NN + 255) / 256, 256, 0, stream>>>(labels, cursor, sorted);
    class_mfma<<<GPERS, 512, 0, stream>>>(features, inb, offsets, counts, sorted,
                                          gsumA, gsumB, gmaxp, gminp);
    finalize_kernel<<<BB, 256, 0, stream>>>(gsumA, gsumB, gmaxp, gminp, counts,
                                            labels, indexes, out);
}